// Round 1
// baseline (1490.938 us; speedup 1.0000x reference)
//
#include <hip/hip_runtime.h>
#include <hip/hip_bf16.h>

// GCN layer on MI355X: out = relu((adj+I) @ (x@W) + b)
// N=16384, NFEAT=256, NCLASS=64.
// Strategy: HBM-bound on adj (1.07 GB fp32, read once). Big GEMM in bf16 MFMA
// (16x16x32), fragments loaded DIRECTLY from global (no LDS, no barriers):
//   A-frag: lane(m=lane&15,quad=lane>>4) reads adj[row][k0+quad*8 ..+8] as
//           8 contiguous fp32 (2x dwordx4), converts to bf16 in-reg.
//   B-frag: supportT (bf16, [64][16384], 2 MB -> L2-resident per XCD),
//           lane reads supportT[n0+m][k0+quad*8 ..+8] = one dwordx4.
// Software pipeline depth 2 (register double-buffer) keeps HBM saturated.

#define NN 16384
#define NF 256
#define NC 64

typedef __attribute__((ext_vector_type(8))) short bf16x8;
typedef __attribute__((ext_vector_type(4))) float floatx4;

static __device__ __forceinline__ unsigned short f2bf(float f) {
  unsigned u = __builtin_bit_cast(unsigned, f);
  u += 0x7fffu + ((u >> 16) & 1u);   // round-to-nearest-even
  return (unsigned short)(u >> 16);
}

static __device__ __forceinline__ bf16x8 pack8(float4 a, float4 b) {
  union { bf16x8 v; unsigned short s[8]; } u;
  u.s[0] = f2bf(a.x); u.s[1] = f2bf(a.y); u.s[2] = f2bf(a.z); u.s[3] = f2bf(a.w);
  u.s[4] = f2bf(b.x); u.s[5] = f2bf(b.y); u.s[6] = f2bf(b.z); u.s[7] = f2bf(b.w);
  return u.v;
}

// Prologue: support = x @ W (fp32), plus bf16 transpose supportT[c][row].
// Grid: 1024 blocks x 256 threads; each block does 16 rows; each thread one
// (row, 4-class) strip. W row (256 B) is one wave-wide L1 line per k-iter.
__global__ __launch_bounds__(256) void support_kernel(
    const float* __restrict__ x, const float* __restrict__ W,
    float* __restrict__ support, unsigned short* __restrict__ supportT) {
  __shared__ float xs[16][NF + 4];   // +4 pad: r-stride 260 dwords -> 4-bank rotation, conflict-free
  const int t = threadIdx.x;
  const int wgRow = blockIdx.x * 16;
  #pragma unroll
  for (int i = 0; i < 4; ++i) {
    int idx = t + i * 256;           // 1024 float4 = 16 rows x 64 float4
    int r = idx >> 6;
    int c4 = (idx & 63) * 4;
    *(float4*)&xs[r][c4] = *(const float4*)&x[(size_t)(wgRow + r) * NF + c4];
  }
  __syncthreads();
  const int r  = t >> 4;             // 0..15
  const int c4 = (t & 15) * 4;       // 0..60
  float a0 = 0.f, a1 = 0.f, a2 = 0.f, a3 = 0.f;
  #pragma unroll 8
  for (int k = 0; k < NF; ++k) {
    float xv = xs[r][k];
    float4 wv = *(const float4*)&W[k * NC + c4];
    a0 = fmaf(xv, wv.x, a0); a1 = fmaf(xv, wv.y, a1);
    a2 = fmaf(xv, wv.z, a2); a3 = fmaf(xv, wv.w, a3);
  }
  const int row = wgRow + r;
  float4 res; res.x = a0; res.y = a1; res.z = a2; res.w = a3;
  *(float4*)&support[(size_t)row * NC + c4] = res;
  supportT[(size_t)(c4 + 0) * NN + row] = f2bf(a0);
  supportT[(size_t)(c4 + 1) * NN + row] = f2bf(a1);
  supportT[(size_t)(c4 + 2) * NN + row] = f2bf(a2);
  supportT[(size_t)(c4 + 3) * NN + row] = f2bf(a3);
}

// Main: agg = adj @ support (bf16 MFMA), out = relu(agg + support + b).
// Grid: 512 blocks x 128 threads = 1024 waves = one wave per SIMD.
// Each wave: 16 rows x 64 classes, K-loop 16384 in chunks of 32 (unroll 2).
__global__ __launch_bounds__(128) void gcn_agg(
    const float* __restrict__ adj, const unsigned short* __restrict__ supportT,
    const float* __restrict__ support, const float* __restrict__ bias,
    float* __restrict__ out) {
  const int lane = threadIdx.x & 63;
  const int wave = threadIdx.x >> 6;
  const int m    = lane & 15;
  const int quad = lane >> 4;
  const int rowBase = blockIdx.x * 32 + wave * 16;

  const float* ap = adj + (size_t)(rowBase + m) * NN + quad * 8;
  const unsigned short* bp0 = supportT + (size_t)m * NN + quad * 8;
  const unsigned short* bp1 = bp0 + (size_t)16 * NN;
  const unsigned short* bp2 = bp0 + (size_t)32 * NN;
  const unsigned short* bp3 = bp0 + (size_t)48 * NN;

  floatx4 acc0 = {0.f, 0.f, 0.f, 0.f};
  floatx4 acc1 = acc0, acc2 = acc0, acc3 = acc0;

  // Pipeline prologue: stage S0 (k=0) and S1 (k=32)
  float4 a0lo = *(const float4*)(ap + 0);
  float4 a0hi = *(const float4*)(ap + 4);
  bf16x8 b00 = *(const bf16x8*)(bp0 + 0);
  bf16x8 b01 = *(const bf16x8*)(bp1 + 0);
  bf16x8 b02 = *(const bf16x8*)(bp2 + 0);
  bf16x8 b03 = *(const bf16x8*)(bp3 + 0);
  float4 a1lo = *(const float4*)(ap + 32);
  float4 a1hi = *(const float4*)(ap + 36);
  bf16x8 b10 = *(const bf16x8*)(bp0 + 32);
  bf16x8 b11 = *(const bf16x8*)(bp1 + 32);
  bf16x8 b12 = *(const bf16x8*)(bp2 + 32);
  bf16x8 b13 = *(const bf16x8*)(bp3 + 32);

  #pragma unroll 1
  for (int k0 = 64; k0 < NN; k0 += 64) {
    // ---- compute S0 (data loaded last iter), then refill S0 <- k0 ----
    {
      bf16x8 af = pack8(a0lo, a0hi);
      acc0 = __builtin_amdgcn_mfma_f32_16x16x32_bf16(af, b00, acc0, 0, 0, 0);
      acc1 = __builtin_amdgcn_mfma_f32_16x16x32_bf16(af, b01, acc1, 0, 0, 0);
      acc2 = __builtin_amdgcn_mfma_f32_16x16x32_bf16(af, b02, acc2, 0, 0, 0);
      acc3 = __builtin_amdgcn_mfma_f32_16x16x32_bf16(af, b03, acc3, 0, 0, 0);
    }
    a0lo = *(const float4*)(ap + k0);
    a0hi = *(const float4*)(ap + k0 + 4);
    b00 = *(const bf16x8*)(bp0 + k0);
    b01 = *(const bf16x8*)(bp1 + k0);
    b02 = *(const bf16x8*)(bp2 + k0);
    b03 = *(const bf16x8*)(bp3 + k0);
    // ---- compute S1, then refill S1 <- k0+32 ----
    {
      bf16x8 ag = pack8(a1lo, a1hi);
      acc0 = __builtin_amdgcn_mfma_f32_16x16x32_bf16(ag, b10, acc0, 0, 0, 0);
      acc1 = __builtin_amdgcn_mfma_f32_16x16x32_bf16(ag, b11, acc1, 0, 0, 0);
      acc2 = __builtin_amdgcn_mfma_f32_16x16x32_bf16(ag, b12, acc2, 0, 0, 0);
      acc3 = __builtin_amdgcn_mfma_f32_16x16x32_bf16(ag, b13, acc3, 0, 0, 0);
    }
    a1lo = *(const float4*)(ap + k0 + 32);
    a1hi = *(const float4*)(ap + k0 + 36);
    b10 = *(const bf16x8*)(bp0 + k0 + 32);
    b11 = *(const bf16x8*)(bp1 + k0 + 32);
    b12 = *(const bf16x8*)(bp2 + k0 + 32);
    b13 = *(const bf16x8*)(bp3 + k0 + 32);
  }
  // Drain: k = 16320 and 16352
  {
    bf16x8 af = pack8(a0lo, a0hi);
    acc0 = __builtin_amdgcn_mfma_f32_16x16x32_bf16(af, b00, acc0, 0, 0, 0);
    acc1 = __builtin_amdgcn_mfma_f32_16x16x32_bf16(af, b01, acc1, 0, 0, 0);
    acc2 = __builtin_amdgcn_mfma_f32_16x16x32_bf16(af, b02, acc2, 0, 0, 0);
    acc3 = __builtin_amdgcn_mfma_f32_16x16x32_bf16(af, b03, acc3, 0, 0, 0);
    bf16x8 ag = pack8(a1lo, a1hi);
    acc0 = __builtin_amdgcn_mfma_f32_16x16x32_bf16(ag, b10, acc0, 0, 0, 0);
    acc1 = __builtin_amdgcn_mfma_f32_16x16x32_bf16(ag, b11, acc1, 0, 0, 0);
    acc2 = __builtin_amdgcn_mfma_f32_16x16x32_bf16(ag, b12, acc2, 0, 0, 0);
    acc3 = __builtin_amdgcn_mfma_f32_16x16x32_bf16(ag, b13, acc3, 0, 0, 0);
  }

  // Epilogue: C/D layout col = lane&15 (+16*nt), row = quad*4 + reg.
  // out = relu(acc + support(fp32, exact identity term) + b)
  float bv0 = bias[m], bv1 = bias[16 + m], bv2 = bias[32 + m], bv3 = bias[48 + m];
  #pragma unroll
  for (int r = 0; r < 4; ++r) {
    int row = rowBase + quad * 4 + r;
    const float* srow = support + (size_t)row * NC;
    float* orow = out + (size_t)row * NC;
    float v0 = acc0[r] + srow[m]      + bv0;
    float v1 = acc1[r] + srow[16 + m] + bv1;
    float v2 = acc2[r] + srow[32 + m] + bv2;
    float v3 = acc3[r] + srow[48 + m] + bv3;
    orow[m]      = fmaxf(v0, 0.f);
    orow[16 + m] = fmaxf(v1, 0.f);
    orow[32 + m] = fmaxf(v2, 0.f);
    orow[48 + m] = fmaxf(v3, 0.f);
  }
}

extern "C" void kernel_launch(void* const* d_in, const int* in_sizes, int n_in,
                              void* d_out, int out_size, void* d_ws, size_t ws_size,
                              hipStream_t stream) {
  const float* x   = (const float*)d_in[0];   // [16384, 256]
  const float* adj = (const float*)d_in[1];   // [16384, 16384]
  const float* W   = (const float*)d_in[2];   // [256, 64]
  const float* b   = (const float*)d_in[3];   // [64]
  float* out = (float*)d_out;                 // [16384, 64]

  // Workspace layout: [0, 2MB) supportT bf16 [64][16384]; [2MB, 6MB) support fp32 [16384][64]
  unsigned short* supportT = (unsigned short*)d_ws;
  float* support = (float*)((char*)d_ws + (size_t)NC * NN * sizeof(unsigned short));

  support_kernel<<<NN / 16, 256, 0, stream>>>(x, W, support, supportT);
  gcn_agg<<<NN / 32, 128, 0, stream>>>(adj, supportT, support, b, out);
}